// Round 1
// baseline (554.251 us; speedup 1.0000x reference)
//
#include <hip/hip_runtime.h>
#include <math.h>

#define NTOK 4096
#define HDIM 1024
#define NEXP 8
#define IDIM 1408
#define TWO_I 2816
#define BM 128
#define BK 32
#define LDH 56            // fp16 elems per LDS row: 32 + 24 pad -> 112B stride (16B-multiple, 2-way bank alias = free)
#define NRB 72            // max 128-row blocks: 8192 real rows + 8*127 pad <= 9216
#define ROWCAP (NRB * BM)

typedef _Float16 f16x8 __attribute__((ext_vector_type(8)));
typedef float f32x4 __attribute__((ext_vector_type(4)));

__device__ __forceinline__ void cvt_store4(_Float16* dst, float4 v) {
  union { _Float16 h[4]; uint2 u; } p;
  p.h[0] = (_Float16)v.x; p.h[1] = (_Float16)v.y;
  p.h[2] = (_Float16)v.z; p.h[3] = (_Float16)v.w;
  *(uint2*)dst = p.u;
}

extern "C" __global__ void moe_init(int* counts, int* cursor, int* tok) {
  int i = blockIdx.x * 256 + threadIdx.x;
  if (i < NEXP) { counts[i] = 0; cursor[i] = 0; }
  if (i < ROWCAP) tok[i] = -1;
}

// one wave per token: fp32 logits, softmax, top-2
extern "C" __global__ void moe_router(const float* __restrict__ x,
                                      const float* __restrict__ rw,
                                      int* __restrict__ topi,
                                      float* __restrict__ topw,
                                      int* __restrict__ counts) {
  int w = threadIdx.x >> 6, lane = threadIdx.x & 63;
  int t = blockIdx.x * 4 + w;
  float acc[NEXP];
#pragma unroll
  for (int e = 0; e < NEXP; e++) acc[e] = 0.f;
  const float* xp = x + (size_t)t * HDIM;
#pragma unroll 4
  for (int i = 0; i < HDIM / 64; i++) {
    float xv = xp[i * 64 + lane];
#pragma unroll
    for (int e = 0; e < NEXP; e++) acc[e] += xv * rw[e * HDIM + i * 64 + lane];
  }
#pragma unroll
  for (int e = 0; e < NEXP; e++) {
#pragma unroll
    for (int off = 32; off > 0; off >>= 1) acc[e] += __shfl_down(acc[e], off);
  }
  if (lane == 0) {
    float m = acc[0];
    for (int e = 1; e < NEXP; e++) m = fmaxf(m, acc[e]);
    float p[NEXP], s = 0.f;
    for (int e = 0; e < NEXP; e++) { p[e] = __expf(acc[e] - m); s += p[e]; }
    float inv = 1.f / s;
    int i0 = 0; float b0 = p[0];
    for (int e = 1; e < NEXP; e++) if (p[e] > b0) { b0 = p[e]; i0 = e; }
    int i1 = -1; float b1 = -1.f;
    for (int e = 0; e < NEXP; e++) if (e != i0 && p[e] > b1) { b1 = p[e]; i1 = e; }
    topi[t * 2] = i0; topi[t * 2 + 1] = i1;
    topw[t * 2] = b0 * inv; topw[t * 2 + 1] = b1 * inv;
    atomicAdd(&counts[i0], 1); atomicAdd(&counts[i1], 1);
  }
}

extern "C" __global__ void moe_offsets(const int* __restrict__ counts, int* __restrict__ aoff) {
  if (threadIdx.x == 0) {
    int o = 0;
    aoff[0] = 0;
    for (int e = 0; e < NEXP; e++) {
      o += ((counts[e] + BM - 1) / BM) * BM;  // 128-aligned segments
      aoff[e + 1] = o;
    }
  }
}

extern "C" __global__ void moe_scatter(const int* __restrict__ topi, const float* __restrict__ topw,
                                       const int* __restrict__ aoff, int* __restrict__ cursor,
                                       int* __restrict__ tok, float* __restrict__ wrow) {
  int t = blockIdx.x * 256 + threadIdx.x;
  if (t < NTOK) {
#pragma unroll
    for (int k = 0; k < 2; k++) {
      int e = topi[t * 2 + k];
      int pos = atomicAdd(&cursor[e], 1);
      int row = aoff[e] + pos;
      tok[row] = t;
      wrow[row] = topw[t * 2 + k];
    }
  }
}

union SM1 {
  struct { _Float16 a[BM * LDH]; _Float16 b[BM * LDH]; } st;  // 28672 B
  float ubuf[128 * 65];                                        // 33280 B
};

// GEMM1: h[row, 1408] = silu(x@Wg^T) * (x@Wu^T), fp16 MFMA 16x16x32, 128x128 tile
// N-tile j covers gate cols [j*64, j*64+64) and up cols [I + j*64, ...): waves 0,1 gate / 2,3 up
extern "C" __global__ __launch_bounds__(256) void moe_gemm1(
    const float* __restrict__ x, const float* __restrict__ gup,
    const int* __restrict__ aoff, const int* __restrict__ tok,
    _Float16* __restrict__ hbuf) {
  __shared__ __align__(16) SM1 sm;
  int rb = blockIdx.y;
  int row0 = rb * BM;
  if (row0 >= aoff[8]) return;
  int e = 0;
#pragma unroll
  for (int i = 0; i < 8; i++) if (row0 >= aoff[i]) e = i;

  const int tid = threadIdx.x;
  const int lane = tid & 63, wave = tid >> 6;
  const int wm = wave & 1, wn = wave >> 1;
  const int quad = lane >> 4, l15 = lane & 15;
  const int j = blockIdx.x;  // 0..21

  f32x4 acc[4][4];
#pragma unroll
  for (int im = 0; im < 4; im++)
#pragma unroll
    for (int in = 0; in < 4; in++) acc[im][in] = (f32x4){0.f, 0.f, 0.f, 0.f};

  const float* bbase = gup + (size_t)e * TWO_I * HDIM;

  // hoisted per-thread staging sources (constant across K loop)
  const float4* asrc[4]; int tkn[4]; _Float16* adst[4];
  const float4* bsrc[4]; _Float16* bdst[4];
#pragma unroll
  for (int i = 0; i < 4; i++) {
    int c = i * 256 + tid;
    int r = c >> 3, sub = c & 7;
    int t = tok[row0 + r];
    tkn[i] = t;
    asrc[i] = (t >= 0) ? (const float4*)(x + (size_t)t * HDIM) + sub : (const float4*)0;
    adst[i] = &sm.st.a[r * LDH + sub * 4];
    int grow = (r < 64) ? (j * 64 + r) : (IDIM + j * 64 + (r - 64));
    bsrc[i] = (const float4*)(bbase + (size_t)grow * HDIM) + sub;
    bdst[i] = &sm.st.b[r * LDH + sub * 4];
  }

  for (int kb = 0; kb < HDIM / BK; kb++) {
#pragma unroll
    for (int i = 0; i < 4; i++) {
      float4 v = make_float4(0.f, 0.f, 0.f, 0.f);
      if (tkn[i] >= 0) v = asrc[i][kb * 8];
      cvt_store4(adst[i], v);
    }
#pragma unroll
    for (int i = 0; i < 4; i++) cvt_store4(bdst[i], bsrc[i][kb * 8]);
    __syncthreads();
    f16x8 av[4], bv[4];
#pragma unroll
    for (int im = 0; im < 4; im++)
      av[im] = *(const f16x8*)&sm.st.a[(wm * 64 + im * 16 + l15) * LDH + quad * 8];
#pragma unroll
    for (int in = 0; in < 4; in++)
      bv[in] = *(const f16x8*)&sm.st.b[(wn * 64 + in * 16 + l15) * LDH + quad * 8];
#pragma unroll
    for (int im = 0; im < 4; im++)
#pragma unroll
      for (int in = 0; in < 4; in++)
        acc[im][in] = __builtin_amdgcn_mfma_f32_16x16x32_f16(av[im], bv[in], acc[im][in], 0, 0, 0);
    __syncthreads();
  }

  // epilogue: up-waves park u in LDS; gate-waves compute silu(g)*u, store fp16 h
  if (wn == 1) {
#pragma unroll
    for (int im = 0; im < 4; im++)
#pragma unroll
      for (int in = 0; in < 4; in++)
#pragma unroll
        for (int r = 0; r < 4; r++)
          sm.ubuf[(wm * 64 + im * 16 + quad * 4 + r) * 65 + in * 16 + l15] = acc[im][in][r];
  }
  __syncthreads();
  if (wn == 0) {
#pragma unroll
    for (int im = 0; im < 4; im++)
#pragma unroll
      for (int in = 0; in < 4; in++)
#pragma unroll
        for (int r = 0; r < 4; r++) {
          float g = acc[im][in][r];
          float u = sm.ubuf[(wm * 64 + im * 16 + quad * 4 + r) * 65 + in * 16 + l15];
          float hh = g / (1.f + __expf(-g)) * u;
          int row = row0 + wm * 64 + im * 16 + quad * 4 + r;
          hbuf[(size_t)row * IDIM + j * 64 + in * 16 + l15] = (_Float16)hh;
        }
  }
}

// GEMM2: y[row, 1024] = h @ down[e]^T, scaled by gate weight, atomic-add into out[token]
extern "C" __global__ __launch_bounds__(256) void moe_gemm2(
    const _Float16* __restrict__ hbuf, const float* __restrict__ dp,
    const int* __restrict__ aoff, const int* __restrict__ tok,
    const float* __restrict__ wrow, float* __restrict__ out) {
  __shared__ __align__(16) struct { _Float16 a[BM * LDH]; _Float16 b[BM * LDH]; } sm;
  int rb = blockIdx.y;
  int row0 = rb * BM;
  if (row0 >= aoff[8]) return;
  int e = 0;
#pragma unroll
  for (int i = 0; i < 8; i++) if (row0 >= aoff[i]) e = i;

  const int tid = threadIdx.x;
  const int lane = tid & 63, wave = tid >> 6;
  const int wm = wave & 1, wn = wave >> 1;
  const int quad = lane >> 4, l15 = lane & 15;
  const int cb = blockIdx.x;  // 0..7

  f32x4 acc[4][4];
#pragma unroll
  for (int im = 0; im < 4; im++)
#pragma unroll
    for (int in = 0; in < 4; in++) acc[im][in] = (f32x4){0.f, 0.f, 0.f, 0.f};

  const float* bbase = dp + (size_t)e * HDIM * IDIM;

  const uint4* asrc[2]; uint4* adst[2];
  const float4* bsrc[4]; _Float16* bdst[4];
#pragma unroll
  for (int i = 0; i < 2; i++) {
    int c = i * 256 + tid;
    int r = c >> 2, sub = c & 3;
    asrc[i] = (const uint4*)(hbuf + (size_t)(row0 + r) * IDIM) + sub;
    adst[i] = (uint4*)&sm.a[r * LDH + sub * 8];
  }
#pragma unroll
  for (int i = 0; i < 4; i++) {
    int c = i * 256 + tid;
    int r = c >> 3, sub = c & 7;
    bsrc[i] = (const float4*)(bbase + (size_t)(cb * 128 + r) * IDIM) + sub;
    bdst[i] = &sm.b[r * LDH + sub * 4];
  }

  for (int kb = 0; kb < IDIM / BK; kb++) {  // 44 iters
#pragma unroll
    for (int i = 0; i < 2; i++) *adst[i] = asrc[i][kb * 4];
#pragma unroll
    for (int i = 0; i < 4; i++) cvt_store4(bdst[i], bsrc[i][kb * 8]);
    __syncthreads();
    f16x8 av[4], bv[4];
#pragma unroll
    for (int im = 0; im < 4; im++)
      av[im] = *(const f16x8*)&sm.a[(wm * 64 + im * 16 + l15) * LDH + quad * 8];
#pragma unroll
    for (int in = 0; in < 4; in++)
      bv[in] = *(const f16x8*)&sm.b[(wn * 64 + in * 16 + l15) * LDH + quad * 8];
#pragma unroll
    for (int im = 0; im < 4; im++)
#pragma unroll
      for (int in = 0; in < 4; in++)
        acc[im][in] = __builtin_amdgcn_mfma_f32_16x16x32_f16(av[im], bv[in], acc[im][in], 0, 0, 0);
    __syncthreads();
  }

#pragma unroll
  for (int im = 0; im < 4; im++) {
    int rbase = row0 + wm * 64 + im * 16 + quad * 4;
#pragma unroll
    for (int r = 0; r < 4; r++) {
      int row = rbase + r;
      int t = tok[row];
      if (t < 0) continue;
      float wgt = wrow[row];
#pragma unroll
      for (int in = 0; in < 4; in++) {
        int col = cb * 128 + wn * 64 + in * 16 + l15;
        atomicAdd(out + (size_t)t * HDIM + col, acc[im][in][r] * wgt);
      }
    }
  }
}

extern "C" void kernel_launch(void* const* d_in, const int* in_sizes, int n_in,
                              void* d_out, int out_size, void* d_ws, size_t ws_size,
                              hipStream_t stream) {
  const float* x   = (const float*)d_in[0];  // [4096,1024]
  const float* rw  = (const float*)d_in[1];  // [8,1024]
  const float* gup = (const float*)d_in[2];  // [8,2816,1024]
  const float* dp  = (const float*)d_in[3];  // [8,1024,1408]
  float* out = (float*)d_out;

  char* ws = (char*)d_ws;
  int*   counts = (int*)ws;                      // 8
  int*   cursor = counts + 8;                    // 8
  int*   aoff   = cursor + 8;                    // 9
  int*   topi   = (int*)(ws + 128);              // 8192 ints
  float* topw   = (float*)(ws + 32896);          // 8192 floats
  int*   tok    = (int*)(ws + 65664);            // 9216 ints
  float* wrow   = (float*)(ws + 102528);         // 9216 floats
  _Float16* hbuf = (_Float16*)(ws + 139520);     // 9216*1408 fp16 = 25.95 MB

  hipMemsetAsync(d_out, 0, (size_t)NTOK * HDIM * sizeof(float), stream);
  moe_init<<<(ROWCAP + 255) / 256, 256, 0, stream>>>(counts, cursor, tok);
  moe_router<<<NTOK / 4, 256, 0, stream>>>(x, rw, topi, topw, counts);
  moe_offsets<<<1, 64, 0, stream>>>(counts, aoff);
  moe_scatter<<<(NTOK + 255) / 256, 256, 0, stream>>>(topi, topw, aoff, cursor, tok, wrow);
  moe_gemm1<<<dim3(TWO_I / 128, NRB), 256, 0, stream>>>(x, gup, aoff, tok, hbuf);
  moe_gemm2<<<dim3(HDIM / 128, NRB), 256, 0, stream>>>(hbuf, dp, aoff, tok, wrow, out);
}

// Round 2
// 451.421 us; speedup vs baseline: 1.2278x; 1.2278x over previous
//
#include <hip/hip_runtime.h>
#include <math.h>

#define NTOK 4096
#define HDIM 1024
#define NEXP 8
#define IDIM 1408
#define TWO_I 2816
#define BM 128
#define BK 32
#define NRB 72            // max 128-row blocks: 8192 real rows + 8*127 pad <= 9216
#define ROWCAP (NRB * BM)

typedef _Float16 f16x8 __attribute__((ext_vector_type(8)));
typedef float f32x4 __attribute__((ext_vector_type(4)));

typedef __attribute__((address_space(1))) const unsigned int gu32;
typedef __attribute__((address_space(3))) unsigned int lu32;
__device__ __forceinline__ void async16(const void* g, void* l) {
  // width-16 global->LDS DMA: per-lane global addr, wave-uniform LDS base + lane*16
  __builtin_amdgcn_global_load_lds((gu32*)g, (lu32*)l, 16, 0, 0);
}

extern "C" __global__ void moe_init(int* counts, int* cursor, int* tok) {
  int i = blockIdx.x * 256 + threadIdx.x;
  if (i < NEXP) { counts[i] = 0; cursor[i] = 0; }
  if (i < ROWCAP) tok[i] = -1;
}

// fp32 -> fp16 bulk convert, 8 elems/thread
extern "C" __global__ void moe_cvt(const float* __restrict__ src, _Float16* __restrict__ dst, int n8) {
  int i = blockIdx.x * 256 + threadIdx.x;
  if (i >= n8) return;
  const float4* s = (const float4*)src + (size_t)i * 2;
  float4 a = s[0], b = s[1];
  union { _Float16 h[8]; uint4 u; } p;
  p.h[0] = (_Float16)a.x; p.h[1] = (_Float16)a.y; p.h[2] = (_Float16)a.z; p.h[3] = (_Float16)a.w;
  p.h[4] = (_Float16)b.x; p.h[5] = (_Float16)b.y; p.h[6] = (_Float16)b.z; p.h[7] = (_Float16)b.w;
  ((uint4*)dst)[i] = p.u;
}

// one wave per token: fp32 logits, softmax, top-2 (exact fp32 routing)
extern "C" __global__ void moe_router(const float* __restrict__ x,
                                      const float* __restrict__ rw,
                                      int* __restrict__ topi,
                                      float* __restrict__ topw,
                                      int* __restrict__ counts) {
  int w = threadIdx.x >> 6, lane = threadIdx.x & 63;
  int t = blockIdx.x * 4 + w;
  float acc[NEXP];
#pragma unroll
  for (int e = 0; e < NEXP; e++) acc[e] = 0.f;
  const float* xp = x + (size_t)t * HDIM;
#pragma unroll 4
  for (int i = 0; i < HDIM / 64; i++) {
    float xv = xp[i * 64 + lane];
#pragma unroll
    for (int e = 0; e < NEXP; e++) acc[e] += xv * rw[e * HDIM + i * 64 + lane];
  }
#pragma unroll
  for (int e = 0; e < NEXP; e++) {
#pragma unroll
    for (int off = 32; off > 0; off >>= 1) acc[e] += __shfl_down(acc[e], off);
  }
  if (lane == 0) {
    float m = acc[0];
    for (int e = 1; e < NEXP; e++) m = fmaxf(m, acc[e]);
    float p[NEXP], s = 0.f;
    for (int e = 0; e < NEXP; e++) { p[e] = __expf(acc[e] - m); s += p[e]; }
    float inv = 1.f / s;
    int i0 = 0; float b0 = p[0];
    for (int e = 1; e < NEXP; e++) if (p[e] > b0) { b0 = p[e]; i0 = e; }
    int i1 = -1; float b1 = -1.f;
    for (int e = 0; e < NEXP; e++) if (e != i0 && p[e] > b1) { b1 = p[e]; i1 = e; }
    topi[t * 2] = i0; topi[t * 2 + 1] = i1;
    topw[t * 2] = b0 * inv; topw[t * 2 + 1] = b1 * inv;
    atomicAdd(&counts[i0], 1); atomicAdd(&counts[i1], 1);
  }
}

extern "C" __global__ void moe_offsets(const int* __restrict__ counts, int* __restrict__ aoff) {
  if (threadIdx.x == 0) {
    int o = 0;
    aoff[0] = 0;
    for (int e = 0; e < NEXP; e++) {
      o += ((counts[e] + BM - 1) / BM) * BM;  // 128-aligned segments
      aoff[e + 1] = o;
    }
  }
}

extern "C" __global__ void moe_scatter(const int* __restrict__ topi, const float* __restrict__ topw,
                                       const int* __restrict__ aoff, int* __restrict__ cursor,
                                       int* __restrict__ tok, float* __restrict__ wrow,
                                       int* __restrict__ rows) {
  int t = blockIdx.x * 256 + threadIdx.x;
  if (t < NTOK) {
#pragma unroll
    for (int k = 0; k < 2; k++) {
      int e = topi[t * 2 + k];
      int pos = atomicAdd(&cursor[e], 1);
      int row = aoff[e] + pos;
      tok[row] = t;
      wrow[row] = topw[t * 2 + k];
      rows[t * 2 + k] = row;
    }
  }
}

union SM1 {
  struct { _Float16 a[BM * BK]; _Float16 b[BM * BK]; } st;  // 16384 B, 64 B rows
  _Float16 ubuf[BM * 66];                                   // 16896 B (epilogue u exchange)
};

// GEMM1: h[row, 1408] = silu(x@Wg^T) * (x@Wu^T); fp16 MFMA, 128x128 tile,
// m97-style global_load_lds staging. N-tile j: rows 0-63 of B = gate cols, 64-127 = up cols.
extern "C" __global__ __launch_bounds__(256) void moe_gemm1(
    const _Float16* __restrict__ xh, const _Float16* __restrict__ guph,
    const int* __restrict__ aoff, const int* __restrict__ tok,
    _Float16* __restrict__ hbuf) {
  __shared__ __align__(16) SM1 sm;
  int row0 = blockIdx.y * BM;
  if (row0 >= aoff[8]) return;
  int e = 0;
#pragma unroll
  for (int i = 0; i < 8; i++) if (row0 >= aoff[i]) e = i;

  const int tid = threadIdx.x;
  const int lane = tid & 63, w = tid >> 6;
  const int wm = w & 1, wn = w >> 1;
  const int quad = lane >> 4, l15 = lane & 15;
  const int j = blockIdx.x;  // 0..21

  f32x4 acc[4][4];
#pragma unroll
  for (int im = 0; im < 4; im++)
#pragma unroll
    for (int in = 0; in < 4; in++) acc[im][in] = (f32x4){0.f, 0.f, 0.f, 0.f};

  // staging sources: chunk c = w and w+4; each chunk = 16 rows x 32 halves (1 KB)
  const int lq = lane >> 2;        // row within chunk
  const int ls = lane & 3;         // 16B slot within row
  const int rA0 = w * 16 + lq, rA1 = rA0 + 64;
  int tA0 = tok[row0 + rA0]; tA0 = tA0 < 0 ? 0 : tA0;   // pad rows clamp; outputs discarded
  int tA1 = tok[row0 + rA1]; tA1 = tA1 < 0 ? 0 : tA1;
  const _Float16* gA0 = xh + (size_t)tA0 * HDIM + ls * 8;
  const _Float16* gA1 = xh + (size_t)tA1 * HDIM + ls * 8;
  const _Float16* eb = guph + (size_t)e * TWO_I * HDIM;
  const _Float16* gB0 = eb + (size_t)(j * 64 + rA0) * HDIM + ls * 8;          // gate rows
  const _Float16* gB1 = eb + (size_t)(IDIM + j * 64 + rA0) * HDIM + ls * 8;   // up rows
  _Float16* lA0 = &sm.st.a[w * 512];
  _Float16* lA1 = &sm.st.a[(w + 4) * 512];
  _Float16* lB0 = &sm.st.b[w * 512];
  _Float16* lB1 = &sm.st.b[(w + 4) * 512];

  for (int kb = 0; kb < HDIM / BK; kb++) {
    async16(gA0, lA0); async16(gA1, lA1);
    async16(gB0, lB0); async16(gB1, lB1);
    gA0 += BK; gA1 += BK; gB0 += BK; gB1 += BK;
    __syncthreads();
    f16x8 av[4], bv[4];
#pragma unroll
    for (int im = 0; im < 4; im++)
      av[im] = *(const f16x8*)&sm.st.a[(wm * 64 + im * 16 + l15) * BK + quad * 8];
#pragma unroll
    for (int in = 0; in < 4; in++)
      bv[in] = *(const f16x8*)&sm.st.b[(wn * 64 + in * 16 + l15) * BK + quad * 8];
#pragma unroll
    for (int im = 0; im < 4; im++)
#pragma unroll
      for (int in = 0; in < 4; in++)
        acc[im][in] = __builtin_amdgcn_mfma_f32_16x16x32_f16(av[im], bv[in], acc[im][in], 0, 0, 0);
    __syncthreads();
  }

  // epilogue: up-waves park u (fp16) in LDS; gate-waves compute silu(g)*u, store fp16 h
  if (wn == 1) {
#pragma unroll
    for (int im = 0; im < 4; im++)
#pragma unroll
      for (int in = 0; in < 4; in++)
#pragma unroll
        for (int r = 0; r < 4; r++)
          sm.ubuf[(wm * 64 + im * 16 + quad * 4 + r) * 66 + in * 16 + l15] = (_Float16)acc[im][in][r];
  }
  __syncthreads();
  if (wn == 0) {
#pragma unroll
    for (int im = 0; im < 4; im++)
#pragma unroll
      for (int in = 0; in < 4; in++)
#pragma unroll
        for (int r = 0; r < 4; r++) {
          float g = acc[im][in][r];
          float u = (float)sm.ubuf[(wm * 64 + im * 16 + quad * 4 + r) * 66 + in * 16 + l15];
          float hh = g / (1.f + __expf(-g)) * u;
          int row = row0 + wm * 64 + im * 16 + quad * 4 + r;
          hbuf[(size_t)row * IDIM + j * 64 + in * 16 + l15] = (_Float16)hh;
        }
  }
}

// GEMM2: y[row, 1024] = (h @ down[e]^T) * wrow[row], fp16 out to yh (no atomics)
extern "C" __global__ __launch_bounds__(256) void moe_gemm2(
    const _Float16* __restrict__ hbuf, const _Float16* __restrict__ dph,
    const int* __restrict__ aoff, const float* __restrict__ wrow,
    _Float16* __restrict__ yh) {
  __shared__ __align__(16) struct { _Float16 a[BM * BK]; _Float16 b[BM * BK]; } sm;
  int row0 = blockIdx.y * BM;
  if (row0 >= aoff[8]) return;
  int e = 0;
#pragma unroll
  for (int i = 0; i < 8; i++) if (row0 >= aoff[i]) e = i;

  const int tid = threadIdx.x;
  const int lane = tid & 63, w = tid >> 6;
  const int wm = w & 1, wn = w >> 1;
  const int quad = lane >> 4, l15 = lane & 15;
  const int cb = blockIdx.x;  // 0..7

  f32x4 acc[4][4];
#pragma unroll
  for (int im = 0; im < 4; im++)
#pragma unroll
    for (int in = 0; in < 4; in++) acc[im][in] = (f32x4){0.f, 0.f, 0.f, 0.f};

  const int lq = lane >> 2, ls = lane & 3;
  const int rA0 = w * 16 + lq;
  const _Float16* gA0 = hbuf + (size_t)(row0 + rA0) * IDIM + ls * 8;
  const _Float16* gA1 = gA0 + (size_t)64 * IDIM;
  const _Float16* eb = dph + (size_t)e * HDIM * IDIM;
  const _Float16* gB0 = eb + (size_t)(cb * 128 + rA0) * IDIM + ls * 8;
  const _Float16* gB1 = gB0 + (size_t)64 * IDIM;
  _Float16* lA0 = &sm.a[w * 512];
  _Float16* lA1 = &sm.a[(w + 4) * 512];
  _Float16* lB0 = &sm.b[w * 512];
  _Float16* lB1 = &sm.b[(w + 4) * 512];

  for (int kb = 0; kb < IDIM / BK; kb++) {  // 44 iters
    async16(gA0, lA0); async16(gA1, lA1);
    async16(gB0, lB0); async16(gB1, lB1);
    gA0 += BK; gA1 += BK; gB0 += BK; gB1 += BK;
    __syncthreads();
    f16x8 av[4], bv[4];
#pragma unroll
    for (int im = 0; im < 4; im++)
      av[im] = *(const f16x8*)&sm.a[(wm * 64 + im * 16 + l15) * BK + quad * 8];
#pragma unroll
    for (int in = 0; in < 4; in++)
      bv[in] = *(const f16x8*)&sm.b[(wn * 64 + in * 16 + l15) * BK + quad * 8];
#pragma unroll
    for (int im = 0; im < 4; im++)
#pragma unroll
      for (int in = 0; in < 4; in++)
        acc[im][in] = __builtin_amdgcn_mfma_f32_16x16x32_f16(av[im], bv[in], acc[im][in], 0, 0, 0);
    __syncthreads();
  }

#pragma unroll
  for (int im = 0; im < 4; im++) {
#pragma unroll
    for (int r = 0; r < 4; r++) {
      int row = row0 + wm * 64 + im * 16 + quad * 4 + r;
      float wgt = wrow[row];  // pad rows: finite poison, never read back
#pragma unroll
      for (int in = 0; in < 4; in++) {
        int col = cb * 128 + wn * 64 + in * 16 + l15;
        yh[(size_t)row * HDIM + col] = (_Float16)(acc[im][in][r] * wgt);
      }
    }
  }
}

// out[t, :] = y[rowA(t), :] + y[rowB(t), :]
extern "C" __global__ void moe_combine(const _Float16* __restrict__ yh,
                                       const int* __restrict__ rows,
                                       float* __restrict__ out) {
  int i = blockIdx.x * 256 + threadIdx.x;  // over T*H/8 = 524288
  int t = i >> 7, c8 = i & 127;
  int rA = rows[t * 2], rB = rows[t * 2 + 1];
  union { uint4 u; _Float16 h[8]; } pa, pb;
  pa.u = ((const uint4*)(yh + (size_t)rA * HDIM))[c8];
  pb.u = ((const uint4*)(yh + (size_t)rB * HDIM))[c8];
  float4 o0, o1;
  o0.x = (float)pa.h[0] + (float)pb.h[0]; o0.y = (float)pa.h[1] + (float)pb.h[1];
  o0.z = (float)pa.h[2] + (float)pb.h[2]; o0.w = (float)pa.h[3] + (float)pb.h[3];
  o1.x = (float)pa.h[4] + (float)pb.h[4]; o1.y = (float)pa.h[5] + (float)pb.h[5];
  o1.z = (float)pa.h[6] + (float)pb.h[6]; o1.w = (float)pa.h[7] + (float)pb.h[7];
  ((float4*)out)[(size_t)i * 2] = o0;
  ((float4*)out)[(size_t)i * 2 + 1] = o1;
}

extern "C" void kernel_launch(void* const* d_in, const int* in_sizes, int n_in,
                              void* d_out, int out_size, void* d_ws, size_t ws_size,
                              hipStream_t stream) {
  const float* x   = (const float*)d_in[0];  // [4096,1024]
  const float* rw  = (const float*)d_in[1];  // [8,1024]
  const float* gup = (const float*)d_in[2];  // [8,2816,1024]
  const float* dp  = (const float*)d_in[3];  // [8,1024,1408]
  float* out = (float*)d_out;

  char* ws = (char*)d_ws;
  int*   counts = (int*)ws;                       // @0
  int*   cursor = (int*)(ws + 64);
  int*   aoff   = (int*)(ws + 128);
  int*   topi   = (int*)(ws + 4096);              // 8192 ints
  float* topw   = (float*)(ws + 36864);           // 8192 floats
  int*   tok    = (int*)(ws + 69632);             // 9216 ints
  float* wrow   = (float*)(ws + 106496);          // 9216 floats
  int*   rows   = (int*)(ws + 143360);            // 8192 ints
  _Float16* xh   = (_Float16*)(ws + 176128);      // 8.39 MB
  _Float16* guph = (_Float16*)(ws + 8564736);     // 46.14 MB
  _Float16* dph  = (_Float16*)(ws + 54702080);    // 23.07 MB
  _Float16* hbuf = (_Float16*)(ws + 77770752);    // 25.95 MB
  _Float16* yh   = (_Float16*)(ws + 103723008);   // 18.87 MB -> total 122.6 MB

  moe_init<<<(ROWCAP + 255) / 256, 256, 0, stream>>>(counts, cursor, tok);
  moe_router<<<NTOK / 4, 256, 0, stream>>>(x, rw, topi, topw, counts);
  moe_offsets<<<1, 64, 0, stream>>>(counts, aoff);
  moe_scatter<<<(NTOK + 255) / 256, 256, 0, stream>>>(topi, topw, aoff, cursor, tok, wrow, rows);
  moe_cvt<<<(NTOK * HDIM / 8 + 255) / 256, 256, 0, stream>>>(x, xh, NTOK * HDIM / 8);
  moe_cvt<<<(NEXP * TWO_I * HDIM / 8 + 255) / 256, 256, 0, stream>>>(gup, guph, NEXP * TWO_I * HDIM / 8);
  moe_cvt<<<(NEXP * HDIM * IDIM / 8 + 255) / 256, 256, 0, stream>>>(dp, dph, NEXP * HDIM * IDIM / 8);
  moe_gemm1<<<dim3(TWO_I / 128, NRB), 256, 0, stream>>>(xh, guph, aoff, tok, hbuf);
  moe_gemm2<<<dim3(HDIM / 128, NRB), 256, 0, stream>>>(hbuf, dph, aoff, wrow, yh);
  moe_combine<<<NTOK * HDIM / 8 / 256, 256, 0, stream>>>(yh, rows, out);
}

// Round 3
// 336.845 us; speedup vs baseline: 1.6454x; 1.3401x over previous
//
#include <hip/hip_runtime.h>
#include <math.h>

#define NTOK 4096
#define HDIM 1024
#define NEXP 8
#define IDIM 1408
#define TWO_I 2816
#define BM 128
#define BK 32
#define NRB 72            // max 128-row blocks: 8192 real rows + 8*127 pad <= 9216
#define ROWCAP (NRB * BM)

typedef _Float16 f16x8 __attribute__((ext_vector_type(8)));
typedef float f32x4 __attribute__((ext_vector_type(4)));

typedef __attribute__((address_space(1))) const unsigned int gu32;
typedef __attribute__((address_space(3))) unsigned int lu32;
__device__ __forceinline__ void async16(const void* g, void* l) {
  // width-16 global->LDS DMA: per-lane global addr, wave-uniform LDS base + lane*16
  __builtin_amdgcn_global_load_lds((gu32*)g, (lu32*)l, 16, 0, 0);
}

extern "C" __global__ void moe_init(int* counts, int* cursor, int* tok) {
  int i = blockIdx.x * 256 + threadIdx.x;
  if (i < NEXP) { counts[i] = 0; cursor[i] = 0; }
  if (i < ROWCAP) tok[i] = -1;
}

// fp32 -> fp16 bulk convert, 8 elems/thread
extern "C" __global__ void moe_cvt(const float* __restrict__ src, _Float16* __restrict__ dst, int n8) {
  int i = blockIdx.x * 256 + threadIdx.x;
  if (i >= n8) return;
  const float4* s = (const float4*)src + (size_t)i * 2;
  float4 a = s[0], b = s[1];
  union { _Float16 h[8]; uint4 u; } p;
  p.h[0] = (_Float16)a.x; p.h[1] = (_Float16)a.y; p.h[2] = (_Float16)a.z; p.h[3] = (_Float16)a.w;
  p.h[4] = (_Float16)b.x; p.h[5] = (_Float16)b.y; p.h[6] = (_Float16)b.z; p.h[7] = (_Float16)b.w;
  ((uint4*)dst)[i] = p.u;
}

// one wave per token: fp32 logits via float4 dot, softmax, top-2. NO atomics.
extern "C" __global__ void moe_router(const float* __restrict__ x,
                                      const float* __restrict__ rw,
                                      int* __restrict__ topi,
                                      float* __restrict__ topw) {
  int w = threadIdx.x >> 6, lane = threadIdx.x & 63;
  int t = blockIdx.x * 4 + w;
  const float4* xp = (const float4*)(x + (size_t)t * HDIM);
  const float4* rp = (const float4*)rw;
  float acc[NEXP];
#pragma unroll
  for (int e = 0; e < NEXP; e++) acc[e] = 0.f;
#pragma unroll
  for (int i = 0; i < HDIM / 256; i++) {  // 4 iters, 9 x 16B loads each
    float4 xv = xp[i * 64 + lane];
#pragma unroll
    for (int e = 0; e < NEXP; e++) {
      float4 rv = rp[e * 256 + i * 64 + lane];
      acc[e] += xv.x * rv.x + xv.y * rv.y + xv.z * rv.z + xv.w * rv.w;
    }
  }
#pragma unroll
  for (int e = 0; e < NEXP; e++) {
#pragma unroll
    for (int off = 32; off > 0; off >>= 1) acc[e] += __shfl_down(acc[e], off);
  }
  if (lane == 0) {
    float m = acc[0];
    for (int e = 1; e < NEXP; e++) m = fmaxf(m, acc[e]);
    float p[NEXP], s = 0.f;
    for (int e = 0; e < NEXP; e++) { p[e] = __expf(acc[e] - m); s += p[e]; }
    float inv = 1.f / s;
    int i0 = 0; float b0 = p[0];
    for (int e = 1; e < NEXP; e++) if (p[e] > b0) { b0 = p[e]; i0 = e; }
    int i1 = -1; float b1 = -1.f;
    for (int e = 0; e < NEXP; e++) if (e != i0 && p[e] > b1) { b1 = p[e]; i1 = e; }
    topi[t * 2] = i0; topi[t * 2 + 1] = i1;
    topw[t * 2] = b0 * inv; topw[t * 2 + 1] = b1 * inv;
  }
}

// LDS-aggregated expert histogram: 128 global atomics total (16 blocks x 8)
extern "C" __global__ void moe_count(const int* __restrict__ topi, int* __restrict__ counts) {
  __shared__ int cnt[NEXP];
  if (threadIdx.x < NEXP) cnt[threadIdx.x] = 0;
  __syncthreads();
  int t = blockIdx.x * 256 + threadIdx.x;
  atomicAdd(&cnt[topi[t * 2]], 1);
  atomicAdd(&cnt[topi[t * 2 + 1]], 1);
  __syncthreads();
  if (threadIdx.x < NEXP) atomicAdd(&counts[threadIdx.x], cnt[threadIdx.x]);
}

extern "C" __global__ void moe_offsets(const int* __restrict__ counts, int* __restrict__ aoff) {
  if (threadIdx.x == 0) {
    int o = 0;
    aoff[0] = 0;
    for (int e = 0; e < NEXP; e++) {
      o += ((counts[e] + BM - 1) / BM) * BM;  // 128-aligned segments
      aoff[e + 1] = o;
    }
  }
}

// block-aggregated scatter: LDS rank + 8 global atomics per block
extern "C" __global__ void moe_scatter(const int* __restrict__ topi, const float* __restrict__ topw,
                                       const int* __restrict__ aoff, int* __restrict__ cursor,
                                       int* __restrict__ tok, float* __restrict__ wrow,
                                       int* __restrict__ rows) {
  __shared__ int cnt[NEXP];
  __shared__ int base[NEXP];
  int tid = threadIdx.x;
  if (tid < NEXP) cnt[tid] = 0;
  __syncthreads();
  int t = blockIdx.x * 256 + tid;
  int e0 = topi[t * 2], e1 = topi[t * 2 + 1];
  int r0 = atomicAdd(&cnt[e0], 1);
  int r1 = atomicAdd(&cnt[e1], 1);
  __syncthreads();
  if (tid < NEXP) base[tid] = atomicAdd(&cursor[tid], cnt[tid]);
  __syncthreads();
  int row0 = aoff[e0] + base[e0] + r0;
  int row1 = aoff[e1] + base[e1] + r1;
  tok[row0] = t; wrow[row0] = topw[t * 2];     rows[t * 2]     = row0;
  tok[row1] = t; wrow[row1] = topw[t * 2 + 1]; rows[t * 2 + 1] = row1;
}

union SM1 {
  struct { _Float16 a[BM * BK]; _Float16 b[BM * BK]; } st;  // 16384 B, 64 B rows
  _Float16 ubuf[BM * 66];                                   // 16896 B (epilogue u exchange)
};

// GEMM1: h[row, 1408] = silu(x@Wg^T) * (x@Wu^T); fp16 MFMA, 128x128 tile,
// m97-style global_load_lds staging. N-tile j: rows 0-63 of B = gate cols, 64-127 = up cols.
extern "C" __global__ __launch_bounds__(256) void moe_gemm1(
    const _Float16* __restrict__ xh, const _Float16* __restrict__ guph,
    const int* __restrict__ aoff, const int* __restrict__ tok,
    _Float16* __restrict__ hbuf) {
  __shared__ __align__(16) SM1 sm;
  int row0 = blockIdx.y * BM;
  if (row0 >= aoff[8]) return;
  int e = 0;
#pragma unroll
  for (int i = 0; i < 8; i++) if (row0 >= aoff[i]) e = i;

  const int tid = threadIdx.x;
  const int lane = tid & 63, w = tid >> 6;
  const int wm = w & 1, wn = w >> 1;
  const int quad = lane >> 4, l15 = lane & 15;
  const int j = blockIdx.x;  // 0..21

  f32x4 acc[4][4];
#pragma unroll
  for (int im = 0; im < 4; im++)
#pragma unroll
    for (int in = 0; in < 4; in++) acc[im][in] = (f32x4){0.f, 0.f, 0.f, 0.f};

  // staging sources: chunk c = w and w+4; each chunk = 16 rows x 32 halves (1 KB)
  const int lq = lane >> 2;        // row within chunk
  const int ls = lane & 3;         // 16B slot within row
  const int rA0 = w * 16 + lq, rA1 = rA0 + 64;
  int tA0 = tok[row0 + rA0]; tA0 = tA0 < 0 ? 0 : tA0;   // pad rows clamp; outputs discarded
  int tA1 = tok[row0 + rA1]; tA1 = tA1 < 0 ? 0 : tA1;
  const _Float16* gA0 = xh + (size_t)tA0 * HDIM + ls * 8;
  const _Float16* gA1 = xh + (size_t)tA1 * HDIM + ls * 8;
  const _Float16* eb = guph + (size_t)e * TWO_I * HDIM;
  const _Float16* gB0 = eb + (size_t)(j * 64 + rA0) * HDIM + ls * 8;          // gate rows
  const _Float16* gB1 = eb + (size_t)(IDIM + j * 64 + rA0) * HDIM + ls * 8;   // up rows
  _Float16* lA0 = &sm.st.a[w * 512];
  _Float16* lA1 = &sm.st.a[(w + 4) * 512];
  _Float16* lB0 = &sm.st.b[w * 512];
  _Float16* lB1 = &sm.st.b[(w + 4) * 512];

  for (int kb = 0; kb < HDIM / BK; kb++) {
    async16(gA0, lA0); async16(gA1, lA1);
    async16(gB0, lB0); async16(gB1, lB1);
    gA0 += BK; gA1 += BK; gB0 += BK; gB1 += BK;
    __syncthreads();
    f16x8 av[4], bv[4];
#pragma unroll
    for (int im = 0; im < 4; im++)
      av[im] = *(const f16x8*)&sm.st.a[(wm * 64 + im * 16 + l15) * BK + quad * 8];
#pragma unroll
    for (int in = 0; in < 4; in++)
      bv[in] = *(const f16x8*)&sm.st.b[(wn * 64 + in * 16 + l15) * BK + quad * 8];
#pragma unroll
    for (int im = 0; im < 4; im++)
#pragma unroll
      for (int in = 0; in < 4; in++)
        acc[im][in] = __builtin_amdgcn_mfma_f32_16x16x32_f16(av[im], bv[in], acc[im][in], 0, 0, 0);
    __syncthreads();
  }

  // epilogue: up-waves park u (fp16) in LDS; gate-waves compute silu(g)*u, store fp16 h
  if (wn == 1) {
#pragma unroll
    for (int im = 0; im < 4; im++)
#pragma unroll
      for (int in = 0; in < 4; in++)
#pragma unroll
        for (int r = 0; r < 4; r++)
          sm.ubuf[(wm * 64 + im * 16 + quad * 4 + r) * 66 + in * 16 + l15] = (_Float16)acc[im][in][r];
  }
  __syncthreads();
  if (wn == 0) {
#pragma unroll
    for (int im = 0; im < 4; im++)
#pragma unroll
      for (int in = 0; in < 4; in++)
#pragma unroll
        for (int r = 0; r < 4; r++) {
          float g = acc[im][in][r];
          float u = (float)sm.ubuf[(wm * 64 + im * 16 + quad * 4 + r) * 66 + in * 16 + l15];
          float hh = g / (1.f + __expf(-g)) * u;
          int row = row0 + wm * 64 + im * 16 + quad * 4 + r;
          hbuf[(size_t)row * IDIM + j * 64 + in * 16 + l15] = (_Float16)hh;
        }
  }
}

// GEMM2: y[row, 1024] = (h @ down[e]^T) * wrow[row], fp16 out to yh (no atomics)
extern "C" __global__ __launch_bounds__(256) void moe_gemm2(
    const _Float16* __restrict__ hbuf, const _Float16* __restrict__ dph,
    const int* __restrict__ aoff, const float* __restrict__ wrow,
    _Float16* __restrict__ yh) {
  __shared__ __align__(16) struct { _Float16 a[BM * BK]; _Float16 b[BM * BK]; } sm;
  int row0 = blockIdx.y * BM;
  if (row0 >= aoff[8]) return;
  int e = 0;
#pragma unroll
  for (int i = 0; i < 8; i++) if (row0 >= aoff[i]) e = i;

  const int tid = threadIdx.x;
  const int lane = tid & 63, w = tid >> 6;
  const int wm = w & 1, wn = w >> 1;
  const int quad = lane >> 4, l15 = lane & 15;
  const int cb = blockIdx.x;  // 0..7

  f32x4 acc[4][4];
#pragma unroll
  for (int im = 0; im < 4; im++)
#pragma unroll
    for (int in = 0; in < 4; in++) acc[im][in] = (f32x4){0.f, 0.f, 0.f, 0.f};

  const int lq = lane >> 2, ls = lane & 3;
  const int rA0 = w * 16 + lq;
  const _Float16* gA0 = hbuf + (size_t)(row0 + rA0) * IDIM + ls * 8;
  const _Float16* gA1 = gA0 + (size_t)64 * IDIM;
  const _Float16* eb = dph + (size_t)e * HDIM * IDIM;
  const _Float16* gB0 = eb + (size_t)(cb * 128 + rA0) * IDIM + ls * 8;
  const _Float16* gB1 = gB0 + (size_t)64 * IDIM;
  _Float16* lA0 = &sm.a[w * 512];
  _Float16* lA1 = &sm.a[(w + 4) * 512];
  _Float16* lB0 = &sm.b[w * 512];
  _Float16* lB1 = &sm.b[(w + 4) * 512];

  for (int kb = 0; kb < IDIM / BK; kb++) {  // 44 iters
    async16(gA0, lA0); async16(gA1, lA1);
    async16(gB0, lB0); async16(gB1, lB1);
    gA0 += BK; gA1 += BK; gB0 += BK; gB1 += BK;
    __syncthreads();
    f16x8 av[4], bv[4];
#pragma unroll
    for (int im = 0; im < 4; im++)
      av[im] = *(const f16x8*)&sm.a[(wm * 64 + im * 16 + l15) * BK + quad * 8];
#pragma unroll
    for (int in = 0; in < 4; in++)
      bv[in] = *(const f16x8*)&sm.b[(wn * 64 + in * 16 + l15) * BK + quad * 8];
#pragma unroll
    for (int im = 0; im < 4; im++)
#pragma unroll
      for (int in = 0; in < 4; in++)
        acc[im][in] = __builtin_amdgcn_mfma_f32_16x16x32_f16(av[im], bv[in], acc[im][in], 0, 0, 0);
    __syncthreads();
  }

#pragma unroll
  for (int im = 0; im < 4; im++) {
#pragma unroll
    for (int r = 0; r < 4; r++) {
      int row = row0 + wm * 64 + im * 16 + quad * 4 + r;
      float wgt = wrow[row];  // pad rows: finite poison, never read back
#pragma unroll
      for (int in = 0; in < 4; in++) {
        int col = cb * 128 + wn * 64 + in * 16 + l15;
        yh[(size_t)row * HDIM + col] = (_Float16)(acc[im][in][r] * wgt);
      }
    }
  }
}

// out[t, :] = y[rowA(t), :] + y[rowB(t), :]
extern "C" __global__ void moe_combine(const _Float16* __restrict__ yh,
                                       const int* __restrict__ rows,
                                       float* __restrict__ out) {
  int i = blockIdx.x * 256 + threadIdx.x;  // over T*H/8 = 524288
  int t = i >> 7, c8 = i & 127;
  int rA = rows[t * 2], rB = rows[t * 2 + 1];
  union { uint4 u; _Float16 h[8]; } pa, pb;
  pa.u = ((const uint4*)(yh + (size_t)rA * HDIM))[c8];
  pb.u = ((const uint4*)(yh + (size_t)rB * HDIM))[c8];
  float4 o0, o1;
  o0.x = (float)pa.h[0] + (float)pb.h[0]; o0.y = (float)pa.h[1] + (float)pb.h[1];
  o0.z = (float)pa.h[2] + (float)pb.h[2]; o0.w = (float)pa.h[3] + (float)pb.h[3];
  o1.x = (float)pa.h[4] + (float)pb.h[4]; o1.y = (float)pa.h[5] + (float)pb.h[5];
  o1.z = (float)pa.h[6] + (float)pb.h[6]; o1.w = (float)pa.h[7] + (float)pb.h[7];
  ((float4*)out)[(size_t)i * 2] = o0;
  ((float4*)out)[(size_t)i * 2 + 1] = o1;
}

extern "C" void kernel_launch(void* const* d_in, const int* in_sizes, int n_in,
                              void* d_out, int out_size, void* d_ws, size_t ws_size,
                              hipStream_t stream) {
  const float* x   = (const float*)d_in[0];  // [4096,1024]
  const float* rw  = (const float*)d_in[1];  // [8,1024]
  const float* gup = (const float*)d_in[2];  // [8,2816,1024]
  const float* dp  = (const float*)d_in[3];  // [8,1024,1408]
  float* out = (float*)d_out;

  char* ws = (char*)d_ws;
  int*   counts = (int*)ws;                       // @0
  int*   cursor = (int*)(ws + 64);
  int*   aoff   = (int*)(ws + 128);
  int*   topi   = (int*)(ws + 4096);              // 8192 ints
  float* topw   = (float*)(ws + 36864);           // 8192 floats
  int*   tok    = (int*)(ws + 69632);             // 9216 ints
  float* wrow   = (float*)(ws + 106496);          // 9216 floats
  int*   rows   = (int*)(ws + 143360);            // 8192 ints
  _Float16* xh   = (_Float16*)(ws + 176128);      // 8.39 MB
  _Float16* guph = (_Float16*)(ws + 8564736);     // 46.14 MB
  _Float16* dph  = (_Float16*)(ws + 54702080);    // 23.07 MB
  _Float16* hbuf = (_Float16*)(ws + 77770752);    // 25.95 MB
  _Float16* yh   = (_Float16*)(ws + 103723008);   // 18.87 MB -> total 122.6 MB

  moe_init<<<(ROWCAP + 255) / 256, 256, 0, stream>>>(counts, cursor, tok);
  moe_router<<<NTOK / 4, 256, 0, stream>>>(x, rw, topi, topw);
  moe_count<<<NTOK / 256, 256, 0, stream>>>(topi, counts);
  moe_offsets<<<1, 64, 0, stream>>>(counts, aoff);
  moe_scatter<<<NTOK / 256, 256, 0, stream>>>(topi, topw, aoff, cursor, tok, wrow, rows);
  moe_cvt<<<(NTOK * HDIM / 8 + 255) / 256, 256, 0, stream>>>(x, xh, NTOK * HDIM / 8);
  moe_cvt<<<(NEXP * TWO_I * HDIM / 8 + 255) / 256, 256, 0, stream>>>(gup, guph, NEXP * TWO_I * HDIM / 8);
  moe_cvt<<<(NEXP * HDIM * IDIM / 8 + 255) / 256, 256, 0, stream>>>(dp, dph, NEXP * HDIM * IDIM / 8);
  moe_gemm1<<<dim3(TWO_I / 128, NRB), 256, 0, stream>>>(xh, guph, aoff, tok, hbuf);
  moe_gemm2<<<dim3(HDIM / 128, NRB), 256, 0, stream>>>(hbuf, dph, aoff, wrow, yh);
  moe_combine<<<NTOK * HDIM / 8 / 256, 256, 0, stream>>>(yh, rows, out);
}

// Round 4
// 331.391 us; speedup vs baseline: 1.6725x; 1.0165x over previous
//
#include <hip/hip_runtime.h>
#include <math.h>

#define NTOK 4096
#define HDIM 1024
#define NEXP 8
#define IDIM 1408
#define TWO_I 2816
#define BM 128
#define BK 32
#define NRB 72            // max 128-row blocks: 8192 real rows + 8*127 pad <= 9216
#define ROWCAP (NRB * BM)

typedef _Float16 f16x8 __attribute__((ext_vector_type(8)));
typedef float f32x4 __attribute__((ext_vector_type(4)));

typedef __attribute__((address_space(1))) const unsigned int gu32;
typedef __attribute__((address_space(3))) unsigned int lu32;
__device__ __forceinline__ void async16(const void* g, void* l) {
  __builtin_amdgcn_global_load_lds((gu32*)g, (lu32*)l, 16, 0, 0);
}

// 128-aligned segment prefix from counts (uniform scalar work, once per block)
__device__ __forceinline__ void seg_prefix(const int* __restrict__ counts, int* aof) {
  int o = 0; aof[0] = 0;
#pragma unroll
  for (int i = 0; i < 8; i++) { o += (counts[i] + 127) & ~127; aof[i + 1] = o; }
}

extern "C" __global__ void moe_init(int* counts, int* cursor, int* tok) {
  int i = blockIdx.x * 256 + threadIdx.x;
  if (i < NEXP) { counts[i] = 0; cursor[i] = 0; }
  if (i < ROWCAP) tok[i] = -1;
}

// fp32 -> fp16 bulk convert of gate_up and down weights in one launch
#define NG8 (NEXP * TWO_I * HDIM / 8)   // 2883584
#define ND8 (NEXP * HDIM * IDIM / 8)    // 1441792
extern "C" __global__ void moe_cvtw(const float* __restrict__ gup, const float* __restrict__ dp,
                                    _Float16* __restrict__ guph, _Float16* __restrict__ dph) {
  int i = blockIdx.x * 256 + threadIdx.x;
  const float4* s; uint4* d; size_t idx;
  if (i < NG8) { s = (const float4*)gup; d = (uint4*)guph; idx = i; }
  else if (i < NG8 + ND8) { s = (const float4*)dp; d = (uint4*)dph; idx = i - NG8; }
  else return;
  float4 a = s[idx * 2], b = s[idx * 2 + 1];
  union { _Float16 h[8]; uint4 u; } p;
  p.h[0] = (_Float16)a.x; p.h[1] = (_Float16)a.y; p.h[2] = (_Float16)a.z; p.h[3] = (_Float16)a.w;
  p.h[4] = (_Float16)b.x; p.h[5] = (_Float16)b.y; p.h[6] = (_Float16)b.z; p.h[7] = (_Float16)b.w;
  d[idx] = p.u;
}

// one wave per token: fp32 logits via float4 dot, softmax, top-2; also writes xh (fp16 x)
extern "C" __global__ void moe_router(const float* __restrict__ x,
                                      const float* __restrict__ rw,
                                      int* __restrict__ topi,
                                      float* __restrict__ topw,
                                      _Float16* __restrict__ xh) {
  int w = threadIdx.x >> 6, lane = threadIdx.x & 63;
  int t = blockIdx.x * 4 + w;
  const float4* xp = (const float4*)(x + (size_t)t * HDIM);
  const float4* rp = (const float4*)rw;
  float acc[NEXP];
#pragma unroll
  for (int e = 0; e < NEXP; e++) acc[e] = 0.f;
#pragma unroll
  for (int i = 0; i < HDIM / 256; i++) {  // 4 iters
    float4 xv = xp[i * 64 + lane];
    union { _Float16 h[4]; uint2 u; } pk;
    pk.h[0] = (_Float16)xv.x; pk.h[1] = (_Float16)xv.y;
    pk.h[2] = (_Float16)xv.z; pk.h[3] = (_Float16)xv.w;
    *(uint2*)(xh + (size_t)t * HDIM + i * 256 + lane * 4) = pk.u;
#pragma unroll
    for (int e = 0; e < NEXP; e++) {
      float4 rv = rp[e * 256 + i * 64 + lane];
      acc[e] += xv.x * rv.x + xv.y * rv.y + xv.z * rv.z + xv.w * rv.w;
    }
  }
#pragma unroll
  for (int e = 0; e < NEXP; e++) {
#pragma unroll
    for (int off = 32; off > 0; off >>= 1) acc[e] += __shfl_down(acc[e], off);
  }
  if (lane == 0) {
    float m = acc[0];
    for (int e = 1; e < NEXP; e++) m = fmaxf(m, acc[e]);
    float p[NEXP], s = 0.f;
    for (int e = 0; e < NEXP; e++) { p[e] = __expf(acc[e] - m); s += p[e]; }
    float inv = 1.f / s;
    int i0 = 0; float b0 = p[0];
    for (int e = 1; e < NEXP; e++) if (p[e] > b0) { b0 = p[e]; i0 = e; }
    int i1 = -1; float b1 = -1.f;
    for (int e = 0; e < NEXP; e++) if (e != i0 && p[e] > b1) { b1 = p[e]; i1 = e; }
    topi[t * 2] = i0; topi[t * 2 + 1] = i1;
    topw[t * 2] = b0 * inv; topw[t * 2 + 1] = b1 * inv;
  }
}

// LDS-aggregated expert histogram: 8 global atomics per block
extern "C" __global__ void moe_count(const int* __restrict__ topi, int* __restrict__ counts) {
  __shared__ int cnt[NEXP];
  if (threadIdx.x < NEXP) cnt[threadIdx.x] = 0;
  __syncthreads();
  int t = blockIdx.x * 256 + threadIdx.x;
  atomicAdd(&cnt[topi[t * 2]], 1);
  atomicAdd(&cnt[topi[t * 2 + 1]], 1);
  __syncthreads();
  if (threadIdx.x < NEXP) atomicAdd(&counts[threadIdx.x], cnt[threadIdx.x]);
}

// block-aggregated scatter: LDS rank + 8 global atomics per block; aoff inline
extern "C" __global__ void moe_scatter(const int* __restrict__ topi, const float* __restrict__ topw,
                                       const int* __restrict__ counts, int* __restrict__ cursor,
                                       int* __restrict__ tok, float* __restrict__ wrow,
                                       int* __restrict__ rows) {
  __shared__ int cnt[NEXP];
  __shared__ int base[NEXP];
  int aof[9]; seg_prefix(counts, aof);
  int tid = threadIdx.x;
  if (tid < NEXP) cnt[tid] = 0;
  __syncthreads();
  int t = blockIdx.x * 256 + tid;
  int e0 = topi[t * 2], e1 = topi[t * 2 + 1];
  int r0 = atomicAdd(&cnt[e0], 1);
  int r1 = atomicAdd(&cnt[e1], 1);
  __syncthreads();
  if (tid < NEXP) base[tid] = atomicAdd(&cursor[tid], cnt[tid]);
  __syncthreads();
  int row0 = aof[e0] + base[e0] + r0;
  int row1 = aof[e1] + base[e1] + r1;
  tok[row0] = t; wrow[row0] = topw[t * 2];     rows[t * 2]     = row0;
  tok[row1] = t; wrow[row1] = topw[t * 2 + 1]; rows[t * 2 + 1] = row1;
}

union SM1 {
  struct { _Float16 a[BM * BK]; _Float16 b[BM * BK]; } st;  // 16384 B
  _Float16 ubuf[BM * 66];                                   // 16896 B (epilogue u exchange)
};

// GEMM1: h[row, 1408] = silu(x@Wg^T) * (x@Wu^T); fp16 MFMA, 128x128 tile.
// 1D grid 1584 with XCD swizzle: fid%8 = rb-group (9 row-blocks); within an XCD,
// j-half (11 tiles) outer, rb inner -> concurrent working set fits 4MB L2.
extern "C" __global__ __launch_bounds__(256) void moe_gemm1(
    const _Float16* __restrict__ xh, const _Float16* __restrict__ guph,
    const int* __restrict__ counts, const int* __restrict__ tok,
    _Float16* __restrict__ hbuf) {
  __shared__ __align__(16) SM1 sm;
  int aof[9]; seg_prefix(counts, aof);
  int fid = blockIdx.x;
  int g = fid & 7, t7 = fid >> 3;          // t7 in [0,198)
  int jl = t7 % 11, u = t7 / 11;           // u in [0,18)
  int r = u % 9, jh = u / 9;
  int j = jh * 11 + jl;                    // 0..21
  int rb = g * 9 + r;                      // 0..71
  int row0 = rb * BM;
  if (row0 >= aof[8]) return;
  int e = 0;
#pragma unroll
  for (int i = 0; i < 8; i++) if (row0 >= aof[i]) e = i;

  const int tid = threadIdx.x;
  const int lane = tid & 63, w = tid >> 6;
  const int wm = w & 1, wn = w >> 1;
  const int quad = lane >> 4, l15 = lane & 15;

  f32x4 acc[4][4];
#pragma unroll
  for (int im = 0; im < 4; im++)
#pragma unroll
    for (int in = 0; in < 4; in++) acc[im][in] = (f32x4){0.f, 0.f, 0.f, 0.f};

  const int lq = lane >> 2;        // row within 16-row chunk
  const int ls = lane & 3;         // 16B slot within row
  const int rA0 = w * 16 + lq, rA1 = rA0 + 64;
  int tA0 = tok[row0 + rA0]; tA0 = tA0 < 0 ? 0 : tA0;   // pad rows clamp; outputs discarded
  int tA1 = tok[row0 + rA1]; tA1 = tA1 < 0 ? 0 : tA1;
  const _Float16* gA0 = xh + (size_t)tA0 * HDIM + ls * 8;
  const _Float16* gA1 = xh + (size_t)tA1 * HDIM + ls * 8;
  const _Float16* eb = guph + (size_t)e * TWO_I * HDIM;
  const _Float16* gB0 = eb + (size_t)(j * 64 + rA0) * HDIM + ls * 8;          // gate rows
  const _Float16* gB1 = eb + (size_t)(IDIM + j * 64 + rA0) * HDIM + ls * 8;   // up rows
  _Float16* lA0 = &sm.st.a[w * 512];
  _Float16* lA1 = &sm.st.a[(w + 4) * 512];
  _Float16* lB0 = &sm.st.b[w * 512];
  _Float16* lB1 = &sm.st.b[(w + 4) * 512];

  for (int kb = 0; kb < HDIM / BK; kb++) {
    async16(gA0, lA0); async16(gA1, lA1);
    async16(gB0, lB0); async16(gB1, lB1);
    gA0 += BK; gA1 += BK; gB0 += BK; gB1 += BK;
    __syncthreads();
    f16x8 av[4], bv[4];
#pragma unroll
    for (int im = 0; im < 4; im++)
      av[im] = *(const f16x8*)&sm.st.a[(wm * 64 + im * 16 + l15) * BK + quad * 8];
#pragma unroll
    for (int in = 0; in < 4; in++)
      bv[in] = *(const f16x8*)&sm.st.b[(wn * 64 + in * 16 + l15) * BK + quad * 8];
#pragma unroll
    for (int im = 0; im < 4; im++)
#pragma unroll
      for (int in = 0; in < 4; in++)
        acc[im][in] = __builtin_amdgcn_mfma_f32_16x16x32_f16(av[im], bv[in], acc[im][in], 0, 0, 0);
    __syncthreads();
  }

  // epilogue: up-waves park u (fp16) in LDS; gate-waves compute silu(g)*u, store fp16 h
  if (wn == 1) {
#pragma unroll
    for (int im = 0; im < 4; im++)
#pragma unroll
      for (int in = 0; in < 4; in++)
#pragma unroll
        for (int r2 = 0; r2 < 4; r2++)
          sm.ubuf[(wm * 64 + im * 16 + quad * 4 + r2) * 66 + in * 16 + l15] = (_Float16)acc[im][in][r2];
  }
  __syncthreads();
  if (wn == 0) {
#pragma unroll
    for (int im = 0; im < 4; im++)
#pragma unroll
      for (int in = 0; in < 4; in++)
#pragma unroll
        for (int r2 = 0; r2 < 4; r2++) {
          float gg = acc[im][in][r2];
          float uu = (float)sm.ubuf[(wm * 64 + im * 16 + quad * 4 + r2) * 66 + in * 16 + l15];
          float hh = gg / (1.f + __expf(-gg)) * uu;
          int row = row0 + wm * 64 + im * 16 + quad * 4 + r2;
          hbuf[(size_t)row * IDIM + j * 64 + in * 16 + l15] = (_Float16)hh;
        }
  }
}

// GEMM2: y[row, 1024] = (h @ down[e]^T) * wrow[row], fp16 out to yh (no atomics)
// 1D grid 576, same XCD swizzle: fid%8 = rb-group.
extern "C" __global__ __launch_bounds__(256) void moe_gemm2(
    const _Float16* __restrict__ hbuf, const _Float16* __restrict__ dph,
    const int* __restrict__ counts, const float* __restrict__ wrow,
    _Float16* __restrict__ yh) {
  __shared__ __align__(16) struct { _Float16 a[BM * BK]; _Float16 b[BM * BK]; } sm;
  int aof[9]; seg_prefix(counts, aof);
  int fid = blockIdx.x;
  int g = fid & 7, t7 = fid >> 3;   // t7 in [0,72)
  int cb = t7 & 7, r = t7 >> 3;     // cb 0..7, r 0..8
  int rb = g * 9 + r;
  int row0 = rb * BM;
  if (row0 >= aof[8]) return;
  int e = 0;
#pragma unroll
  for (int i = 0; i < 8; i++) if (row0 >= aof[i]) e = i;

  const int tid = threadIdx.x;
  const int lane = tid & 63, w = tid >> 6;
  const int wm = w & 1, wn = w >> 1;
  const int quad = lane >> 4, l15 = lane & 15;

  f32x4 acc[4][4];
#pragma unroll
  for (int im = 0; im < 4; im++)
#pragma unroll
    for (int in = 0; in < 4; in++) acc[im][in] = (f32x4){0.f, 0.f, 0.f, 0.f};

  const int lq = lane >> 2, ls = lane & 3;
  const int rA0 = w * 16 + lq;
  const _Float16* gA0 = hbuf + (size_t)(row0 + rA0) * IDIM + ls * 8;
  const _Float16* gA1 = gA0 + (size_t)64 * IDIM;
  const _Float16* eb = dph + (size_t)e * HDIM * IDIM;
  const _Float16* gB0 = eb + (size_t)(cb * 128 + rA0) * IDIM + ls * 8;
  const _Float16* gB1 = gB0 + (size_t)64 * IDIM;
  _Float16* lA0 = &sm.a[w * 512];
  _Float16* lA1 = &sm.a[(w + 4) * 512];
  _Float16* lB0 = &sm.b[w * 512];
  _Float16* lB1 = &sm.b[(w + 4) * 512];

  for (int kb = 0; kb < IDIM / BK; kb++) {  // 44 iters
    async16(gA0, lA0); async16(gA1, lA1);
    async16(gB0, lB0); async16(gB1, lB1);
    gA0 += BK; gA1 += BK; gB0 += BK; gB1 += BK;
    __syncthreads();
    f16x8 av[4], bv[4];
#pragma unroll
    for (int im = 0; im < 4; im++)
      av[im] = *(const f16x8*)&sm.a[(wm * 64 + im * 16 + l15) * BK + quad * 8];
#pragma unroll
    for (int in = 0; in < 4; in++)
      bv[in] = *(const f16x8*)&sm.b[(wn * 64 + in * 16 + l15) * BK + quad * 8];
#pragma unroll
    for (int im = 0; im < 4; im++)
#pragma unroll
      for (int in = 0; in < 4; in++)
        acc[im][in] = __builtin_amdgcn_mfma_f32_16x16x32_f16(av[im], bv[in], acc[im][in], 0, 0, 0);
    __syncthreads();
  }

#pragma unroll
  for (int im = 0; im < 4; im++) {
#pragma unroll
    for (int r2 = 0; r2 < 4; r2++) {
      int row = row0 + wm * 64 + im * 16 + quad * 4 + r2;
      float wgt = wrow[row];  // pad rows: finite poison, never read back
#pragma unroll
      for (int in = 0; in < 4; in++) {
        int col = cb * 128 + wn * 64 + in * 16 + l15;
        yh[(size_t)row * HDIM + col] = (_Float16)(acc[im][in][r2] * wgt);
      }
    }
  }
}

// out[t, :] = y[rowA(t), :] + y[rowB(t), :]
extern "C" __global__ void moe_combine(const _Float16* __restrict__ yh,
                                       const int* __restrict__ rows,
                                       float* __restrict__ out) {
  int i = blockIdx.x * 256 + threadIdx.x;  // over T*H/8 = 524288
  int t = i >> 7, c8 = i & 127;
  int rA = rows[t * 2], rB = rows[t * 2 + 1];
  union { uint4 u; _Float16 h[8]; } pa, pb;
  pa.u = ((const uint4*)(yh + (size_t)rA * HDIM))[c8];
  pb.u = ((const uint4*)(yh + (size_t)rB * HDIM))[c8];
  float4 o0, o1;
  o0.x = (float)pa.h[0] + (float)pb.h[0]; o0.y = (float)pa.h[1] + (float)pb.h[1];
  o0.z = (float)pa.h[2] + (float)pb.h[2]; o0.w = (float)pa.h[3] + (float)pb.h[3];
  o1.x = (float)pa.h[4] + (float)pb.h[4]; o1.y = (float)pa.h[5] + (float)pb.h[5];
  o1.z = (float)pa.h[6] + (float)pb.h[6]; o1.w = (float)pa.h[7] + (float)pb.h[7];
  ((float4*)out)[(size_t)i * 2] = o0;
  ((float4*)out)[(size_t)i * 2 + 1] = o1;
}

extern "C" void kernel_launch(void* const* d_in, const int* in_sizes, int n_in,
                              void* d_out, int out_size, void* d_ws, size_t ws_size,
                              hipStream_t stream) {
  const float* x   = (const float*)d_in[0];  // [4096,1024]
  const float* rw  = (const float*)d_in[1];  // [8,1024]
  const float* gup = (const float*)d_in[2];  // [8,2816,1024]
  const float* dp  = (const float*)d_in[3];  // [8,1024,1408]
  float* out = (float*)d_out;

  char* ws = (char*)d_ws;
  int*   counts = (int*)ws;                       // @0
  int*   cursor = (int*)(ws + 64);
  int*   topi   = (int*)(ws + 4096);              // 8192 ints
  float* topw   = (float*)(ws + 36864);           // 8192 floats
  int*   tok    = (int*)(ws + 69632);             // 9216 ints
  float* wrow   = (float*)(ws + 106496);          // 9216 floats
  int*   rows   = (int*)(ws + 143360);            // 8192 ints
  _Float16* xh   = (_Float16*)(ws + 176128);      // 8.39 MB
  _Float16* guph = (_Float16*)(ws + 8564736);     // 46.14 MB
  _Float16* dph  = (_Float16*)(ws + 54702080);    // 23.07 MB
  _Float16* hbuf = (_Float16*)(ws + 77770752);    // 25.95 MB
  _Float16* yh   = (_Float16*)(ws + 103723008);   // 18.87 MB -> total 122.6 MB

  moe_init<<<(ROWCAP + 255) / 256, 256, 0, stream>>>(counts, cursor, tok);
  moe_router<<<NTOK / 4, 256, 0, stream>>>(x, rw, topi, topw, xh);
  moe_count<<<NTOK / 256, 256, 0, stream>>>(topi, counts);
  moe_scatter<<<NTOK / 256, 256, 0, stream>>>(topi, topw, counts, cursor, tok, wrow, rows);
  moe_cvtw<<<(NG8 + ND8 + 255) / 256, 256, 0, stream>>>(gup, dp, guph, dph);
  moe_gemm1<<<8 * 22 * 9, 256, 0, stream>>>(xh, guph, counts, tok, hbuf);
  moe_gemm2<<<8 * 8 * 9, 256, 0, stream>>>(hbuf, dph, counts, wrow, yh);
  moe_combine<<<NTOK * HDIM / 8 / 256, 256, 0, stream>>>(yh, rows, out);
}